// Round 10
// baseline (442.223 us; speedup 1.0000x reference)
//
#include <hip/hip_runtime.h>

#define N_OSC 50
#define N_PER 40
#define DT 0.01f
#define STEPS 100
#define BATCH 8192

// ws layout (float offsets)
#define WS_PC     0        // 50*240 = 12000 packed consts
#define WS_DIRECT 12288    // 8192
#define WS_O0     20480    // 100*8192
#define WS_TORQ   839680   // 100*8192 torque accumulator

// ---------------------------------------------------------------------------
// Fused prep + MLP. Blocks [0,800): zero torq; blocks [0,8) pack consts.
// Blocks [800,1312): MLP, 16 batch rows per block.
// Packed consts per osc (stride 240 floats):
//   [0..79]    E: chunk c -> (e0 of unit 2c, e0 of 2c+1, e1 of 2c, e1 of 2c+1)
//   [80..159]  D: chunk c -> (d0 of 2c, d0 of 2c+1, d1 of 2c, d1 of 2c+1)
//   [160..199] W: chunk c -> (w4 of 2c, w4 of 2c+1)
//   [200..239] OB: chunk c -> (ob of 2c, ob of 2c+1)
// ---------------------------------------------------------------------------
__global__ __launch_bounds__(256) void prep_mlp_kernel(
    const float* __restrict__ x,
    const float* __restrict__ fc1_w, const float* __restrict__ fc1_b,
    const float* __restrict__ fc2_w, const float* __restrict__ fc2_b,
    const float* __restrict__ fc3_w, const float* __restrict__ fc3_b,
    const float* __restrict__ fcd_w, const float* __restrict__ fcd_b,
    const float* __restrict__ enc, const float* __restrict__ obias,
    const float* __restrict__ dec, const float* __restrict__ fc4_w,
    float* __restrict__ pc, float* __restrict__ torq,
    float* __restrict__ o0out, float* __restrict__ directout) {
    __shared__ float hs[16 * 132];
    __shared__ float h2s[16 * 132];
    int blk = blockIdx.x;
    int tid = threadIdx.x;

    if (blk < 800) {
        int idx = blk * 256 + tid;
        ((float4*)torq)[idx] = make_float4(0.f, 0.f, 0.f, 0.f);  // 819200 floats
        if (idx < N_OSC * N_PER) {
            int o = idx / N_PER, n = idx - o * N_PER;
            int c = n >> 1, h = n & 1;
            float* base = pc + o * 240;
            base[4 * c + h]           = enc[o * 80 + 2 * n + 0];
            base[4 * c + 2 + h]       = enc[o * 80 + 2 * n + 1];
            base[80 + 4 * c + h]      = dec[o * 80 + n];         // dec[o][0][n]
            base[80 + 4 * c + 2 + h]  = dec[o * 80 + 40 + n];    // dec[o][1][n]
            base[160 + 2 * c + h]     = fc4_w[o * 40 + n];
            base[200 + 2 * c + h]     = obias[o * 40 + n];
        }
        return;
    }

    int r = tid & 15;              // batch row in block
    int jg = tid >> 4;             // 0..15 output-group
    int b0 = (blk - 800) * 16;

    for (int idx = tid; idx < 16 * 128; idx += 256) {
        int rr = idx >> 7, j = idx & 127;
        float x0 = x[(b0 + rr) * 2], x1 = x[(b0 + rr) * 2 + 1];
        float v = fmaf(x0, fc1_w[j * 2], fmaf(x1, fc1_w[j * 2 + 1], fc1_b[j]));
        hs[rr * 132 + j] = fmaxf(v, 0.f);
    }
    __syncthreads();

    if (tid < 16) {
        float s = fcd_b[0];
        #pragma unroll 8
        for (int k = 0; k < 128; k += 4) {
            float4 h4 = *(const float4*)&hs[tid * 132 + k];
            float4 w4 = *(const float4*)&fcd_w[k];
            s = fmaf(h4.x, w4.x, fmaf(h4.y, w4.y, fmaf(h4.z, w4.z, fmaf(h4.w, w4.w, s))));
        }
        directout[b0 + tid] = s;
    }

    for (int pass = 0; pass < 2; ++pass) {
        int j0 = jg * 8 + pass * 4;
        float a0 = fc2_b[j0], a1 = fc2_b[j0 + 1], a2 = fc2_b[j0 + 2], a3 = fc2_b[j0 + 3];
        const float* w0 = fc2_w + j0 * 128;
        const float* w1 = w0 + 128;
        const float* w2 = w0 + 256;
        const float* w3 = w0 + 384;
        #pragma unroll 8
        for (int k = 0; k < 128; k += 4) {
            float4 h4 = *(const float4*)&hs[r * 132 + k];
            float4 q0 = *(const float4*)&w0[k];
            float4 q1 = *(const float4*)&w1[k];
            float4 q2 = *(const float4*)&w2[k];
            float4 q3 = *(const float4*)&w3[k];
            a0 = fmaf(h4.x, q0.x, fmaf(h4.y, q0.y, fmaf(h4.z, q0.z, fmaf(h4.w, q0.w, a0))));
            a1 = fmaf(h4.x, q1.x, fmaf(h4.y, q1.y, fmaf(h4.z, q1.z, fmaf(h4.w, q1.w, a1))));
            a2 = fmaf(h4.x, q2.x, fmaf(h4.y, q2.y, fmaf(h4.z, q2.z, fmaf(h4.w, q2.w, a2))));
            a3 = fmaf(h4.x, q3.x, fmaf(h4.y, q3.y, fmaf(h4.z, q3.z, fmaf(h4.w, q3.w, a3))));
        }
        h2s[r * 132 + j0]     = fmaxf(a0, 0.f);
        h2s[r * 132 + j0 + 1] = fmaxf(a1, 0.f);
        h2s[r * 132 + j0 + 2] = fmaxf(a2, 0.f);
        h2s[r * 132 + j0 + 3] = fmaxf(a3, 0.f);
    }
    __syncthreads();

    for (int pass = 0; pass < 2; ++pass) {
        int j0 = pass * 64 + jg * 4;
        if (j0 >= 100) continue;
        float a0 = fc3_b[j0], a1 = fc3_b[j0 + 1], a2 = fc3_b[j0 + 2], a3 = fc3_b[j0 + 3];
        const float* w0 = fc3_w + j0 * 128;
        const float* w1 = w0 + 128;
        const float* w2 = w0 + 256;
        const float* w3 = w0 + 384;
        #pragma unroll 8
        for (int k = 0; k < 128; k += 4) {
            float4 h4 = *(const float4*)&h2s[r * 132 + k];
            float4 q0 = *(const float4*)&w0[k];
            float4 q1 = *(const float4*)&w1[k];
            float4 q2 = *(const float4*)&w2[k];
            float4 q3 = *(const float4*)&w3[k];
            a0 = fmaf(h4.x, q0.x, fmaf(h4.y, q0.y, fmaf(h4.z, q0.z, fmaf(h4.w, q0.w, a0))));
            a1 = fmaf(h4.x, q1.x, fmaf(h4.y, q1.y, fmaf(h4.z, q1.z, fmaf(h4.w, q1.w, a1))));
            a2 = fmaf(h4.x, q2.x, fmaf(h4.y, q2.y, fmaf(h4.z, q2.z, fmaf(h4.w, q2.w, a2))));
            a3 = fmaf(h4.x, q3.x, fmaf(h4.y, q3.y, fmaf(h4.z, q3.z, fmaf(h4.w, q3.w, a3))));
        }
        o0out[(j0)     * BATCH + b0 + r] = a0;
        o0out[(j0 + 1) * BATCH + b0 + r] = a1;
        o0out[(j0 + 2) * BATCH + b0 + r] = a2;
        o0out[(j0 + 3) * BATCH + b0 + r] = a3;
    }
}

// ---------------------------------------------------------------------------
// Phase A: R7 mapping, 100-step loop in INLINE ASM with hard-clobbered regs.
// Constants live in v12..v71 (loaded by the asm itself) — the register
// allocator cannot remat/spill/reload them. v0..v11 temps, v[72:73] zero
// pair, v[74:75] atomic address. Per chunk i:
//   e0=v[12+4i:13+4i] e1=v[14+4i:15+4i] d0=v[32+4i:33+4i] d1=v[34+4i:35+4i]
//   w=v[52+2i:53+2i] ob=v[62+2i:63+2i]
// Butterfly via v_mov_b32_dpp quad_perm (+v_add), 3-value interleave
// satisfies the 2-wait-state DPP hazard. ug==0 lanes fire the atomic under
// a masked exec, restored immediately.
// ---------------------------------------------------------------------------
__global__ __launch_bounds__(256) void osc_kernel(const float* __restrict__ pc,
                                                  const float* __restrict__ o0init,
                                                  float* __restrict__ torq) {
    int tid = threadIdx.x;
    int w = __builtin_amdgcn_readfirstlane(tid >> 6);
    int lane = tid & 63;
    int W = blockIdx.x * 4 + w;        // 0..25599
    int bg = W / N_OSC;                // 0..511
    int osc = W - bg * N_OSC;          // 0..49
    int ug = lane & 3;
    int b = bg * 16 + (lane >> 2);

    const char* pcb = (const char*)(pc + osc * 240);
    const char* addr1 = pcb + 16 * (ug * 5);   // E at +16i, D at +320+16i
    const char* addr2 = pcb + 8 * (ug * 5);    // W at +640+8i, OB at +800+8i

    float s0 = o0init[(2 * osc) * BATCH + b];
    float s1 = o0init[(2 * osc + 1) * BATCH + b];
    unsigned long long ua = (unsigned long long)(torq + b);
    unsigned int alo = (unsigned int)ua;
    unsigned int ahi = (unsigned int)(ua >> 32);
    unsigned long long mask = __ballot(ug == 0);
    unsigned long long saved = 0;
    int cnt = STEPS;
    float dt = DT;

    asm volatile(
        // ---- load constants into pinned regs ----
        "global_load_dwordx4 v[12:15], %[a1], off\n\t"
        "global_load_dwordx4 v[16:19], %[a1], off offset:16\n\t"
        "global_load_dwordx4 v[20:23], %[a1], off offset:32\n\t"
        "global_load_dwordx4 v[24:27], %[a1], off offset:48\n\t"
        "global_load_dwordx4 v[28:31], %[a1], off offset:64\n\t"
        "global_load_dwordx4 v[32:35], %[a1], off offset:320\n\t"
        "global_load_dwordx4 v[36:39], %[a1], off offset:336\n\t"
        "global_load_dwordx4 v[40:43], %[a1], off offset:352\n\t"
        "global_load_dwordx4 v[44:47], %[a1], off offset:368\n\t"
        "global_load_dwordx4 v[48:51], %[a1], off offset:384\n\t"
        "global_load_dwordx2 v[52:53], %[a2], off offset:640\n\t"
        "global_load_dwordx2 v[54:55], %[a2], off offset:648\n\t"
        "global_load_dwordx2 v[56:57], %[a2], off offset:656\n\t"
        "global_load_dwordx2 v[58:59], %[a2], off offset:664\n\t"
        "global_load_dwordx2 v[60:61], %[a2], off offset:672\n\t"
        "global_load_dwordx2 v[62:63], %[a2], off offset:800\n\t"
        "global_load_dwordx2 v[64:65], %[a2], off offset:808\n\t"
        "global_load_dwordx2 v[66:67], %[a2], off offset:816\n\t"
        "global_load_dwordx2 v[68:69], %[a2], off offset:824\n\t"
        "global_load_dwordx2 v[70:71], %[a2], off offset:832\n\t"
        "v_mov_b32 v72, 0\n\t"
        "v_mov_b32 v73, 0\n\t"
        "v_mov_b32 v74, %[alo]\n\t"
        "v_mov_b32 v75, %[ahi]\n\t"
        "s_waitcnt vmcnt(0)\n\t"
        // ---- step loop ----
        "Losc%=:\n\t"
        "v_mov_b32 v0, %[s0]\n\t"
        "v_mov_b32 v1, %[s0]\n\t"
        "v_mov_b32 v2, %[s1]\n\t"
        "v_mov_b32 v3, %[s1]\n\t"
        // chunk 0
        "v_pk_fma_f32 v[4:5], v[2:3], v[14:15], v[62:63]\n\t"
        "v_pk_fma_f32 v[4:5], v[0:1], v[12:13], v[4:5]\n\t"
        "v_max_f32 v4, 0, v4\n\t"
        "v_max_f32 v5, 0, v5\n\t"
        "v_pk_mul_f32 v[6:7], v[4:5], v[52:53]\n\t"
        "v_pk_mul_f32 v[8:9], v[4:5], v[32:33]\n\t"
        "v_pk_mul_f32 v[10:11], v[4:5], v[34:35]\n\t"
        // chunk 1
        "v_pk_fma_f32 v[4:5], v[2:3], v[18:19], v[64:65]\n\t"
        "v_pk_fma_f32 v[4:5], v[0:1], v[16:17], v[4:5]\n\t"
        "v_max_f32 v4, 0, v4\n\t"
        "v_max_f32 v5, 0, v5\n\t"
        "v_pk_fma_f32 v[6:7], v[4:5], v[54:55], v[6:7]\n\t"
        "v_pk_fma_f32 v[8:9], v[4:5], v[36:37], v[8:9]\n\t"
        "v_pk_fma_f32 v[10:11], v[4:5], v[38:39], v[10:11]\n\t"
        // chunk 2
        "v_pk_fma_f32 v[4:5], v[2:3], v[22:23], v[66:67]\n\t"
        "v_pk_fma_f32 v[4:5], v[0:1], v[20:21], v[4:5]\n\t"
        "v_max_f32 v4, 0, v4\n\t"
        "v_max_f32 v5, 0, v5\n\t"
        "v_pk_fma_f32 v[6:7], v[4:5], v[56:57], v[6:7]\n\t"
        "v_pk_fma_f32 v[8:9], v[4:5], v[40:41], v[8:9]\n\t"
        "v_pk_fma_f32 v[10:11], v[4:5], v[42:43], v[10:11]\n\t"
        // chunk 3
        "v_pk_fma_f32 v[4:5], v[2:3], v[26:27], v[68:69]\n\t"
        "v_pk_fma_f32 v[4:5], v[0:1], v[24:25], v[4:5]\n\t"
        "v_max_f32 v4, 0, v4\n\t"
        "v_max_f32 v5, 0, v5\n\t"
        "v_pk_fma_f32 v[6:7], v[4:5], v[58:59], v[6:7]\n\t"
        "v_pk_fma_f32 v[8:9], v[4:5], v[44:45], v[8:9]\n\t"
        "v_pk_fma_f32 v[10:11], v[4:5], v[46:47], v[10:11]\n\t"
        // chunk 4
        "v_pk_fma_f32 v[4:5], v[2:3], v[30:31], v[70:71]\n\t"
        "v_pk_fma_f32 v[4:5], v[0:1], v[28:29], v[4:5]\n\t"
        "v_max_f32 v4, 0, v4\n\t"
        "v_max_f32 v5, 0, v5\n\t"
        "v_pk_fma_f32 v[6:7], v[4:5], v[60:61], v[6:7]\n\t"
        "v_pk_fma_f32 v[8:9], v[4:5], v[48:49], v[8:9]\n\t"
        "v_pk_fma_f32 v[10:11], v[4:5], v[50:51], v[10:11]\n\t"
        // pair sums: v4=d0s, v5=d1s, v6=vt
        "v_add_f32 v4, v8, v9\n\t"
        "v_add_f32 v5, v10, v11\n\t"
        "v_add_f32 v6, v6, v7\n\t"
        // butterfly xor1 (2-instr gaps satisfy DPP hazard)
        "v_mov_b32_dpp v0, v4 quad_perm:[1,0,3,2] row_mask:0xf bank_mask:0xf\n\t"
        "v_mov_b32_dpp v1, v5 quad_perm:[1,0,3,2] row_mask:0xf bank_mask:0xf\n\t"
        "v_mov_b32_dpp v7, v6 quad_perm:[1,0,3,2] row_mask:0xf bank_mask:0xf\n\t"
        "v_add_f32 v4, v4, v0\n\t"
        "v_add_f32 v5, v5, v1\n\t"
        "v_add_f32 v6, v6, v7\n\t"
        // butterfly xor2
        "v_mov_b32_dpp v0, v4 quad_perm:[2,3,0,1] row_mask:0xf bank_mask:0xf\n\t"
        "v_mov_b32_dpp v1, v5 quad_perm:[2,3,0,1] row_mask:0xf bank_mask:0xf\n\t"
        "v_mov_b32_dpp v7, v6 quad_perm:[2,3,0,1] row_mask:0xf bank_mask:0xf\n\t"
        "v_add_f32 v4, v4, v0\n\t"
        "v_add_f32 v5, v5, v1\n\t"
        "v_add_f32 v6, v6, v7\n\t"
        // state update
        "v_fmac_f32 %[s0], %[dt], v4\n\t"
        "v_fmac_f32 %[s1], %[dt], v5\n\t"
        // atomic from ug==0 lanes
        "s_mov_b64 %[sv], exec\n\t"
        "s_and_b64 exec, exec, %[mk]\n\t"
        "global_atomic_add_f32 v[74:75], v6, off\n\t"
        "s_mov_b64 exec, %[sv]\n\t"
        // bump torq address by one step (32768 B)
        "v_add_co_u32 v74, vcc, 0x8000, v74\n\t"
        "v_addc_co_u32 v75, vcc, 0, v75, vcc\n\t"
        // loop control
        "s_sub_u32 %[cnt], %[cnt], 1\n\t"
        "s_cmp_lg_u32 %[cnt], 0\n\t"
        "s_cbranch_scc1 Losc%=\n\t"
        : [s0]"+v"(s0), [s1]"+v"(s1), [cnt]"+s"(cnt), [sv]"+s"(saved)
        : [a1]"v"(addr1), [a2]"v"(addr2), [alo]"v"(alo), [ahi]"v"(ahi),
          [dt]"v"(dt), [mk]"s"(mask)
        : "memory", "vcc", "scc",
          "v0","v1","v2","v3","v4","v5","v6","v7","v8","v9",
          "v10","v11","v12","v13","v14","v15","v16","v17","v18","v19",
          "v20","v21","v22","v23","v24","v25","v26","v27","v28","v29",
          "v30","v31","v32","v33","v34","v35","v36","v37","v38","v39",
          "v40","v41","v42","v43","v44","v45","v46","v47","v48","v49",
          "v50","v51","v52","v53","v54","v55","v56","v57","v58","v59",
          "v60","v61","v62","v63","v64","v65","v66","v67","v68","v69",
          "v70","v71","v72","v73","v74","v75");
}

// ---------------------------------------------------------------------------
// Phase B: integrate pendulum; 128 blocks x 64 (4x more CUs than R9's 32
// blocks — this stream was a hidden ~50 us of the residue).
// ---------------------------------------------------------------------------
__global__ __launch_bounds__(64) void pend_kernel(const float* __restrict__ x,
                                                  const float* __restrict__ torq,
                                                  const float* __restrict__ direct,
                                                  const float* __restrict__ fc4_b,
                                                  float* __restrict__ out) {
    int b = blockIdx.x * 64 + threadIdx.x;
    float theta = x[2 * b];
    float omega = 0.f;
    float base = direct[b] + fc4_b[0];
    float2* out_l = (float2*)out;             // (100, 8192, 2)
    float* out_t = out + STEPS * BATCH * 2;   // (100, 8192)
    float pf[4];
    #pragma unroll
    for (int j = 0; j < 4; ++j) pf[j] = torq[j * BATCH + b];
    #pragma unroll 4
    for (int s = 0; s < STEPS; ++s) {
        float tq = base + pf[s & 3];
        if (s + 4 < STEPS) pf[s & 3] = torq[(s + 4) * BATCH + b];
        float alpha = tq - __sinf(theta) - 0.1f * omega;   // old theta, old omega
        theta = fmaf(DT, omega, theta);                    // uses old omega
        omega = fmaf(DT, alpha, omega);
        out_l[s * BATCH + b] = make_float2(theta, omega);
        out_t[s * BATCH + b] = tq;
    }
}

extern "C" void kernel_launch(void* const* d_in, const int* in_sizes, int n_in,
                              void* d_out, int out_size, void* d_ws, size_t ws_size,
                              hipStream_t stream) {
    const float* x     = (const float*)d_in[0];
    const float* fc1_w = (const float*)d_in[1];
    const float* fc1_b = (const float*)d_in[2];
    const float* fc2_w = (const float*)d_in[3];
    const float* fc2_b = (const float*)d_in[4];
    const float* fc3_w = (const float*)d_in[5];
    const float* fc3_b = (const float*)d_in[6];
    const float* fcd_w = (const float*)d_in[7];
    const float* fcd_b = (const float*)d_in[8];
    const float* enc   = (const float*)d_in[9];
    const float* obias = (const float*)d_in[10];
    const float* dec   = (const float*)d_in[11];
    const float* fc4_w = (const float*)d_in[12];
    const float* fc4_b = (const float*)d_in[13];
    float* out = (float*)d_out;
    float* ws = (float*)d_ws;

    float* pc      = ws + WS_PC;
    float* direct  = ws + WS_DIRECT;
    float* o0      = ws + WS_O0;
    float* torq    = ws + WS_TORQ;

    hipLaunchKernelGGL(prep_mlp_kernel, dim3(800 + 512), dim3(256), 0, stream,
                       x, fc1_w, fc1_b, fc2_w, fc2_b, fc3_w, fc3_b,
                       fcd_w, fcd_b, enc, obias, dec, fc4_w,
                       pc, torq, o0, direct);
    hipLaunchKernelGGL(osc_kernel, dim3(25600 / 4), dim3(256), 0, stream,
                       pc, o0, torq);
    hipLaunchKernelGGL(pend_kernel, dim3(BATCH / 64), dim3(64), 0, stream,
                       x, torq, direct, fc4_b, out);
}